// Round 14
// baseline (53.604 us; speedup 1.0000x reference)
//
#include <hip/hip_runtime.h>

#define NPROTO 2048
#define NOUT   200
#define LAT    40
#define PBLK   16      // proto-reduction blocks in stage1
#define FBLK   1024    // fused dist+out blocks
#define RPB    32      // rows per fused block
#define NB1    64      // level-1 arrival buckets (one cache line each)
#define WREP   16      // write-phase repeats (VISIBILITY PROBE: put distout in top-5)

// ws layout:
//  floats [0..199]      wsum[200]
//  floats [200..215]    proto_sq partials (16)
//  floats [256..895]    proto_sum partials [16][40]
//  ull    [1024..2047]  packed {min,sum} partials per block
//  ints   [6400 + c*32] level-1 arrival counters, c=0..63 (128B apart)
//  int    [8448]        level-2 arrival counter

__global__ __launch_bounds__(320) void pc_stage1(const float* __restrict__ protos,
                                                 const float* __restrict__ w,
                                                 float* __restrict__ ws) {
    const int b = blockIdx.x;
    const int t = threadIdx.x;
    __shared__ float sred[5];
    __shared__ float sdim[8][40];
    __shared__ float ssq[5];
    if (b == 0) {                                  // reset arrival counters
        if (t < NB1) ((int*)ws)[6400 + t * 32] = 0;
        if (t == NB1) ((int*)ws)[8448] = 0;
    }
    if (b < NOUT) {
        // wsum[b] = sum_p w[b, p] — float4 loads, 512 vectors
        float acc = 0.f;
        const float4* row = (const float4*)(w + b * NPROTO);
        float4 v0 = row[t];
        acc += v0.x + v0.y + v0.z + v0.w;
        if (t < 192) {
            float4 v1 = row[t + 320];
            acc += v1.x + v1.y + v1.z + v1.w;
        }
        #pragma unroll
        for (int off = 32; off > 0; off >>= 1) acc += __shfl_down(acc, off, 64);
        if ((t & 63) == 0) sred[t >> 6] = acc;
        __syncthreads();
        if (t == 0) ws[b] = sred[0] + sred[1] + sred[2] + sred[3] + sred[4];
    } else {
        // proto partial reduction: 16 blocks x 320 threads, d = t%40 invariant
        const int rel = b - NOUT;          // 0..15
        const int d = t % 40, g = t / 40;  // 8 groups of 40
        float sum = 0.f, sq = 0.f;
        for (int idx = rel * 320 + t; idx < NPROTO * LAT; idx += PBLK * 320) {
            float v = protos[idx];          // coalesced; idx%40 == d always
            sum += v;
            sq  += v * v;
        }
        sdim[g][d] = sum;
        #pragma unroll
        for (int off = 32; off > 0; off >>= 1) sq += __shfl_down(sq, off, 64);
        if ((t & 63) == 0) ssq[t >> 6] = sq;
        __syncthreads();
        if (t < 40) {
            float s = 0.f;
            #pragma unroll
            for (int g2 = 0; g2 < 8; ++g2) s += sdim[g2][t];
            ws[256 + rel * 40 + t] = s;
        }
        if (t == 0) ws[200 + rel] = ssq[0] + ssq[1] + ssq[2] + ssq[3] + ssq[4];
    }
}

__device__ __forceinline__ unsigned long long pack2f(float a, float b) {
    union { float f[2]; unsigned long long u; } c;
    c.f[0] = a; c.f[1] = b; return c.u;
}

__global__ __launch_bounds__(256) void pc_distout(const float* __restrict__ x,
                                                  const float* __restrict__ bias,
                                                  float* __restrict__ ws,
                                                  float* __restrict__ out) {
    __shared__ float4 sx[RPB * 10];   // this block's 32 x-rows (5KB)
    __shared__ float  sps[40];
    __shared__ float  spsq;
    __shared__ float2 swb[100];
    __shared__ float2 sbb[100];
    __shared__ float  sd[RPB];
    __shared__ int    islast;
    __shared__ float  fmn[4], fsm[4];
    const int t   = threadIdx.x;
    const int blk = blockIdx.x;

    // cooperative x prefetch: 320 float4, contiguous, all 256 lanes
    {
        const float4* xs = (const float4*)(x + blk * (RPB * LAT));
        sx[t] = xs[t];
        if (t < RPB * 10 - 256) sx[t + 256] = xs[t + 256];
    }

    // fold stage1 partials (kernel-boundary coherent) + stage wsum/bias
    if (t < 40) {
        float s = 0.f;
        #pragma unroll
        for (int j = 0; j < PBLK; ++j) s += ws[256 + j * 40 + t];
        sps[t] = s;
    } else if (t == 40) {
        float s = 0.f;
        #pragma unroll
        for (int j = 0; j < PBLK; ++j) s += ws[200 + j];
        spsq = s;
    }
    if (t >= 56 && t < 156) swb[t - 56]  = ((const float2*)ws)[t - 56];
    if (t >= 156)           sbb[t - 156] = ((const float2*)bias)[t - 156];
    __syncthreads();

    // phase 1: threads 0..31 (wave 0) compute d for this block's 32 rows
    float pmn = 0.f, psm = 0.f;
    if (t < RPB) {
        float ssq2 = 0.f, dot = 0.f;
        #pragma unroll
        for (int k = 0; k < 10; ++k) {
            float4 v = sx[t * 10 + k];
            ssq2 += v.x * v.x + v.y * v.y + v.z * v.z + v.w * v.w;
            dot  += v.x * sps[4 * k] + v.y * sps[4 * k + 1] +
                    v.z * sps[4 * k + 2] + v.w * sps[4 * k + 3];
        }
        const float d = sqrtf(2048.f * ssq2 - 2.f * dot + spsq);
        sd[t] = d;
        float mn = d, sm = d;
        #pragma unroll
        for (int off = 16; off > 0; off >>= 1) {   // 32 active lanes, same wave
            mn = fminf(mn, __shfl_down(mn, off, 64));
            sm += __shfl_down(sm, off, 64);
        }
        pmn = mn; psm = sm;
    }
    __syncthreads();

    // phase 2 (x WREP=16, VISIBILITY PROBE): write 32x200 output slab.
    // Makes distout ~45-55us so it appears in rocprof top-5 with counters.
    // t_other = dur - 16 * 2.4us (write-pass cost measured in r12).
    float2* o = (float2*)(out + 2);          // 8B-aligned
    const int base = blk * (RPB * 100);
    #pragma unroll 1
    for (int rep = 0; rep < WREP; ++rep) {
        for (int idx = t; idx < RPB * 100; idx += 256) {
            const int i = idx / 100;             // row within block (magic-mul)
            const int j = idx - i * 100;         // column pair
            const float  dd = sd[i];
            const float2 wv = swb[j];
            const float2 bv = sbb[j];
            float2 r;
            r.x = dd * wv.x + bv.x;
            r.y = dd * wv.y + bv.y;
            o[base + idx] = r;
        }
        asm volatile("" ::: "memory");       // keep all reps' stores live
    }

    // hierarchical arrival (r7-proven)
    unsigned long long* pptr = (unsigned long long*)ws + 1024;
    int* cnt1 = (int*)ws + 6400;
    int* cnt2 = (int*)ws + 8448;
    if (t == 0) {
        __hip_atomic_store(pptr + blk, pack2f(pmn, psm),
                           __ATOMIC_RELAXED, __HIP_MEMORY_SCOPE_AGENT);
        asm volatile("s_waitcnt vmcnt(0)" ::: "memory");  // partial is at LLC
        const int c = blk & (NB1 - 1);
        int last = 0;
        int p1 = __hip_atomic_fetch_add(cnt1 + c * 32, 1, __ATOMIC_RELAXED,
                                        __HIP_MEMORY_SCOPE_AGENT);
        if (p1 == FBLK / NB1 - 1) {
            int p2 = __hip_atomic_fetch_add(cnt2, 1, __ATOMIC_RELAXED,
                                            __HIP_MEMORY_SCOPE_AGENT);
            last = (p2 == NB1 - 1);
        }
        islast = last;
    }
    __syncthreads();

    // last-arriving block reduces all 1024 partials
    if (islast) {
        float mn = 3.4e38f, sm = 0.f;
        #pragma unroll
        for (int j = 0; j < FBLK / 256; ++j) {
            unsigned long long v = __hip_atomic_load(pptr + j * 256 + t,
                                                     __ATOMIC_RELAXED,
                                                     __HIP_MEMORY_SCOPE_AGENT);
            union { unsigned long long u; float f[2]; } c2; c2.u = v;
            mn = fminf(mn, c2.f[0]);
            sm += c2.f[1];
        }
        #pragma unroll
        for (int off = 32; off > 0; off >>= 1) {
            mn = fminf(mn, __shfl_down(mn, off, 64));
            sm += __shfl_down(sm, off, 64);
        }
        if ((t & 63) == 0) { fmn[t >> 6] = mn; fsm[t >> 6] = sm; }
        __syncthreads();
        if (t == 0) {
            out[0] = fminf(fminf(fmn[0], fmn[1]), fminf(fmn[2], fmn[3]));
            out[1] = (fsm[0] + fsm[1] + fsm[2] + fsm[3]) * (1.0f / 32768.0f);
        }
    }
}

extern "C" void kernel_launch(void* const* d_in, const int* in_sizes, int n_in,
                              void* d_out, int out_size, void* d_ws, size_t ws_size,
                              hipStream_t stream) {
    const float* x      = (const float*)d_in[0];
    const float* protos = (const float*)d_in[1];
    const float* w      = (const float*)d_in[2];
    const float* bias   = (const float*)d_in[3];
    float* out = (float*)d_out;
    float* ws  = (float*)d_ws;

    pc_stage1<<<NOUT + PBLK, 320, 0, stream>>>(protos, w, ws);
    pc_distout<<<FBLK, 256, 0, stream>>>(x, bias, ws, out);
}

// Round 15
// 17.900 us; speedup vs baseline: 2.9947x; 2.9947x over previous
//
#include <hip/hip_runtime.h>

#define NPROTO 2048
#define NOUT   200
#define LAT    40
#define PBLK   16      // proto-reduction blocks in stage1
#define FBLK   1024    // fused dist+out blocks
#define RPB    32      // rows per fused block
#define NB1    64      // level-1 arrival buckets (one cache line each)

// ws layout:
//  floats [0..199]      wsum[200]
//  floats [200..215]    proto_sq partials (16)
//  floats [256..895]    proto_sum partials [16][40]
//  ull    [1024..2047]  packed {min,sum} partials per block
//  ints   [6400 + c*32] level-1 arrival counters, c=0..63 (128B apart)
//  int    [8448]        level-2 arrival counter

__global__ __launch_bounds__(320) void pc_stage1(const float* __restrict__ protos,
                                                 const float* __restrict__ w,
                                                 float* __restrict__ ws) {
    const int b = blockIdx.x;
    const int t = threadIdx.x;
    __shared__ float sred[5];
    __shared__ float sdim[8][40];
    __shared__ float ssq[5];
    if (b == 0) {                                  // reset arrival counters
        if (t < NB1) ((int*)ws)[6400 + t * 32] = 0;
        if (t == NB1) ((int*)ws)[8448] = 0;
    }
    if (b < NOUT) {
        // wsum[b] = sum_p w[b, p] — float4 loads, 512 vectors
        float acc = 0.f;
        const float4* row = (const float4*)(w + b * NPROTO);
        float4 v0 = row[t];
        acc += v0.x + v0.y + v0.z + v0.w;
        if (t < 192) {
            float4 v1 = row[t + 320];
            acc += v1.x + v1.y + v1.z + v1.w;
        }
        #pragma unroll
        for (int off = 32; off > 0; off >>= 1) acc += __shfl_down(acc, off, 64);
        if ((t & 63) == 0) sred[t >> 6] = acc;
        __syncthreads();
        if (t == 0) ws[b] = sred[0] + sred[1] + sred[2] + sred[3] + sred[4];
    } else {
        // proto partial reduction: 16 blocks x 320 threads, d = t%40 invariant
        const int rel = b - NOUT;          // 0..15
        const int d = t % 40, g = t / 40;  // 8 groups of 40
        float sum = 0.f, sq = 0.f;
        for (int idx = rel * 320 + t; idx < NPROTO * LAT; idx += PBLK * 320) {
            float v = protos[idx];          // coalesced; idx%40 == d always
            sum += v;
            sq  += v * v;
        }
        sdim[g][d] = sum;
        #pragma unroll
        for (int off = 32; off > 0; off >>= 1) sq += __shfl_down(sq, off, 64);
        if ((t & 63) == 0) ssq[t >> 6] = sq;
        __syncthreads();
        if (t < 40) {
            float s = 0.f;
            #pragma unroll
            for (int g2 = 0; g2 < 8; ++g2) s += sdim[g2][t];
            ws[256 + rel * 40 + t] = s;
        }
        if (t == 0) ws[200 + rel] = ssq[0] + ssq[1] + ssq[2] + ssq[3] + ssq[4];
    }
}

__device__ __forceinline__ unsigned long long pack2f(float a, float b) {
    union { float f[2]; unsigned long long u; } c;
    c.f[0] = a; c.f[1] = b; return c.u;
}

__global__ __launch_bounds__(256) void pc_distout(const float* __restrict__ x,
                                                  const float* __restrict__ bias,
                                                  float* __restrict__ ws,
                                                  float* __restrict__ out) {
    __shared__ float4 sx[RPB * 10];   // this block's 32 x-rows (5KB)
    __shared__ float  sps[40];
    __shared__ float  spsq;
    __shared__ float2 swb[100];
    __shared__ float2 sbb[100];
    __shared__ float  sd[RPB];
    __shared__ int    islast;
    __shared__ float  fmn[4], fsm[4];
    const int t   = threadIdx.x;
    const int blk = blockIdx.x;

    // cooperative x prefetch: 320 float4, contiguous, all 256 lanes
    {
        const float4* xs = (const float4*)(x + blk * (RPB * LAT));
        sx[t] = xs[t];
        if (t < RPB * 10 - 256) sx[t + 256] = xs[t + 256];
    }

    // fold stage1 partials (kernel-boundary coherent) + stage wsum/bias
    if (t < 40) {
        float s = 0.f;
        #pragma unroll
        for (int j = 0; j < PBLK; ++j) s += ws[256 + j * 40 + t];
        sps[t] = s;
    } else if (t == 40) {
        float s = 0.f;
        #pragma unroll
        for (int j = 0; j < PBLK; ++j) s += ws[200 + j];
        spsq = s;
    }
    if (t >= 56 && t < 156) swb[t - 56]  = ((const float2*)ws)[t - 56];
    if (t >= 156)           sbb[t - 156] = ((const float2*)bias)[t - 156];
    __syncthreads();

    // phase 1: threads 0..31 (wave 0) compute d for this block's 32 rows
    float pmn = 0.f, psm = 0.f;
    if (t < RPB) {
        float ssq2 = 0.f, dot = 0.f;
        #pragma unroll
        for (int k = 0; k < 10; ++k) {
            float4 v = sx[t * 10 + k];
            ssq2 += v.x * v.x + v.y * v.y + v.z * v.z + v.w * v.w;
            dot  += v.x * sps[4 * k] + v.y * sps[4 * k + 1] +
                    v.z * sps[4 * k + 2] + v.w * sps[4 * k + 3];
        }
        const float d = sqrtf(2048.f * ssq2 - 2.f * dot + spsq);
        sd[t] = d;
        float mn = d, sm = d;
        #pragma unroll
        for (int off = 16; off > 0; off >>= 1) {   // 32 active lanes, same wave
            mn = fminf(mn, __shfl_down(mn, off, 64));
            sm += __shfl_down(sm, off, 64);
        }
        pmn = mn; psm = sm;
    }
    __syncthreads();

    // phase 2: write 32x200 output slab with SYSTEM-SCOPE stores (sc0 sc1 =
    // L2-bypass/write-through). r14 probe: stores retire into L2 at ~11 TB/s
    // but 26MB sits dirty (fits in 8x4MB L2) and drains to HBM at only
    // ~3.76 TB/s, largely as a serialized end-of-dispatch flush (~7us).
    // Bypassing L2 streams the output to HBM DURING the loop instead.
    unsigned long long* o = (unsigned long long*)(out + 2);   // 8B-aligned
    const int base = blk * (RPB * 100);
    for (int idx = t; idx < RPB * 100; idx += 256) {
        const int i = idx / 100;             // row within block (magic-mul)
        const int j = idx - i * 100;         // column pair
        const float  dd = sd[i];
        const float2 wv = swb[j];
        const float2 bv = sbb[j];
        __hip_atomic_store(o + base + idx,
                           pack2f(dd * wv.x + bv.x, dd * wv.y + bv.y),
                           __ATOMIC_RELAXED, __HIP_MEMORY_SCOPE_SYSTEM);
    }

    // hierarchical arrival (r7-proven)
    unsigned long long* pptr = (unsigned long long*)ws + 1024;
    int* cnt1 = (int*)ws + 6400;
    int* cnt2 = (int*)ws + 8448;
    if (t == 0) {
        __hip_atomic_store(pptr + blk, pack2f(pmn, psm),
                           __ATOMIC_RELAXED, __HIP_MEMORY_SCOPE_AGENT);
        asm volatile("s_waitcnt vmcnt(0)" ::: "memory");  // partial is at LLC
        const int c = blk & (NB1 - 1);
        int last = 0;
        int p1 = __hip_atomic_fetch_add(cnt1 + c * 32, 1, __ATOMIC_RELAXED,
                                        __HIP_MEMORY_SCOPE_AGENT);
        if (p1 == FBLK / NB1 - 1) {
            int p2 = __hip_atomic_fetch_add(cnt2, 1, __ATOMIC_RELAXED,
                                            __HIP_MEMORY_SCOPE_AGENT);
            last = (p2 == NB1 - 1);
        }
        islast = last;
    }
    __syncthreads();

    // last-arriving block reduces all 1024 partials
    if (islast) {
        float mn = 3.4e38f, sm = 0.f;
        #pragma unroll
        for (int j = 0; j < FBLK / 256; ++j) {
            unsigned long long v = __hip_atomic_load(pptr + j * 256 + t,
                                                     __ATOMIC_RELAXED,
                                                     __HIP_MEMORY_SCOPE_AGENT);
            union { unsigned long long u; float f[2]; } c2; c2.u = v;
            mn = fminf(mn, c2.f[0]);
            sm += c2.f[1];
        }
        #pragma unroll
        for (int off = 32; off > 0; off >>= 1) {
            mn = fminf(mn, __shfl_down(mn, off, 64));
            sm += __shfl_down(sm, off, 64);
        }
        if ((t & 63) == 0) { fmn[t >> 6] = mn; fsm[t >> 6] = sm; }
        __syncthreads();
        if (t == 0) {
            out[0] = fminf(fminf(fmn[0], fmn[1]), fminf(fmn[2], fmn[3]));
            out[1] = (fsm[0] + fsm[1] + fsm[2] + fsm[3]) * (1.0f / 32768.0f);
        }
    }
}

extern "C" void kernel_launch(void* const* d_in, const int* in_sizes, int n_in,
                              void* d_out, int out_size, void* d_ws, size_t ws_size,
                              hipStream_t stream) {
    const float* x      = (const float*)d_in[0];
    const float* protos = (const float*)d_in[1];
    const float* w      = (const float*)d_in[2];
    const float* bias   = (const float*)d_in[3];
    float* out = (float*)d_out;
    float* ws  = (float*)d_ws;

    pc_stage1<<<NOUT + PBLK, 320, 0, stream>>>(protos, w, ws);
    pc_distout<<<FBLK, 256, 0, stream>>>(x, bias, ws, out);
}